// Round 13
// baseline (143.149 us; speedup 1.0000x reference)
//
#include <hip/hip_runtime.h>
#include <hip/hip_bf16.h>
#include <stdint.h>

// GRU cell, B=32768, IN=256, H=256, CONCAT=512. Fused bf16-MFMA kernel.
// R17 = R16 (rcp gates + pk2 + 4-ks barrier phases, hot ~47-51us) with the
// B prefetch DEEPENED from 1 group (2 ks) to 3 ks lookahead at ZERO register
// delta: Bb[2][12] (2x48 VGPR) -> Bb[4][6] (4 rotating 1-ks buffers, same
// 96 VGPR total). Theory: per-group time ~3000cyc vs ~400cyc MFMA issue;
// R16 showed barriers cost only ~500cyc each -> residual exposure is
// B-fragment L2/L3 latency (~600-1500cyc under 8-wave contention) at
// 1-group cover. Buffer for ks is filled at ks-3. Slab/barrier cadence,
// MFMA order, gates/tail/epilogue bit-identical to R16.
// Spill detector: WRITE_SIZE ~36 MB expected.

typedef float  f32x4  __attribute__((ext_vector_type(4)));
typedef __bf16 bf16x8 __attribute__((ext_vector_type(8)));
typedef short  s16x8  __attribute__((ext_vector_type(8)));

#define B_TOT   32768
#define MT      64
#define WRZ_ELEMS (512*512)

__device__ __forceinline__ unsigned short f2b(float f) {
    union { float f; unsigned int u; } v; v.f = f;
    unsigned int r = (v.u + 0x7FFFu + ((v.u >> 16) & 1u)) >> 16;  // RNE
    return (unsigned short)r;
}
__device__ __forceinline__ float b2f(unsigned short b) {
    union { unsigned int u; float f; } v; v.u = ((unsigned int)b) << 16;
    return v.f;
}
__device__ __forceinline__ ushort2 pk2(float a, float b) {   // v_cvt_pk_bf16_f32
    __hip_bfloat162 t = __float22bfloat162_rn(make_float2(a, b));
    union { __hip_bfloat162 h; ushort2 u; } c; c.h = t; return c.u;
}
// rcp-based gates: v_rcp_f32 is ~1 ulp; error invisible vs bf16 rounding.
__device__ __forceinline__ float sigmoid_f(float x) {
    return __builtin_amdgcn_rcpf(1.0f + __expf(-x));
}
__device__ __forceinline__ float tanh_f(float x) {
    return 1.0f - 2.0f * __builtin_amdgcn_rcpf(__expf(2.0f * x) + 1.0f);
}

// bf16 LDS tile 64x512 (64 KB), XOR-swizzled at 16B (8-elem) granularity.
__device__ __forceinline__ int lds_idx(int row, int col) {
    return row * 512 + ((((col >> 3) ^ (row & 7)) << 3) | (col & 7));
}

// 8 fp32 (2x f32x4) -> 8 bf16 -> one 16B LDS write (stage slab stash).
__device__ __forceinline__ void stash8(unsigned short* dst, f32x4 a, f32x4 b) {
    union { ushort2 u2[4]; s16x8 v; } pk;
    pk.u2[0] = pk2(a[0], a[1]); pk.u2[1] = pk2(a[2], a[3]);
    pk.u2[2] = pk2(b[0], b[1]); pk.u2[3] = pk2(b[2], b[3]);
    *reinterpret_cast<s16x8*>(dst) = pk.v;
}
__device__ __forceinline__ f32x4 ld4(const float* p) {
    return *reinterpret_cast<const f32x4*>(p);
}

// ---------------------------------------------------------------------------
// Prep (unchanged): fp32 -> bf16 ks-major per-wave fragment pages.
// wrz page (wave w): [ks 0..15][jn 0..3][512]; jn 0,1 r-cols, jn 2,3 z-cols.
// wg  page (wave w): [ks 0..15][j 0..1][512]; k<256 whx, k>=256 whh.
// ---------------------------------------------------------------------------
__global__ void prep_weights(const float* __restrict__ wr,
                             const float* __restrict__ wz,
                             const float* __restrict__ whh,
                             const float* __restrict__ whx,
                             unsigned short* __restrict__ wrz,
                             unsigned short* __restrict__ wg) {
    const int b = blockIdx.x;
    const int t = threadIdx.x;
    union { s16x8 v; unsigned short u[8]; } tmp;

    if (b < 128) {                       // wrz: block = (w, ks)
        int w = b >> 4, ks = b & 15;
        int jn = t >> 6, l = t & 63;
        int kbase = ks * 32 + ((l >> 4) << 3);
        int n = 32 * w + ((jn & 1) << 4) + (l & 15);
        const float* src = (jn < 2) ? wr : wz;
        #pragma unroll
        for (int jj = 0; jj < 8; ++jj)
            tmp.u[jj] = f2b(src[(kbase + jj) * 256 + n]);
        *reinterpret_cast<s16x8*>(wrz + (size_t)w * 32768 + ks * 2048 + t * 8) = tmp.v;
    } else {                             // wg: block = (w, ks-pair)
        int b2 = b - 128;
        int w = b2 >> 3, ksp = b2 & 7;
        int ksl = t >> 7, j = (t >> 6) & 1, l = t & 63;
        int ks = ksp * 2 + ksl;
        int kbase = ks * 32 + ((l >> 4) << 3);
        int n = 32 * w + (j << 4) + (l & 15);
        #pragma unroll
        for (int jj = 0; jj < 8; ++jj) {
            int k = kbase + jj;
            tmp.u[jj] = f2b((k < 256) ? whx[k * 256 + n] : whh[(k - 256) * 256 + n]);
        }
        *reinterpret_cast<s16x8*>(wg + (size_t)w * 16384 + ksp * 2048 + t * 8) = tmp.v;
    }
}

// ---------------------------------------------------------------------------
// Fused GRU: 512 threads (8 waves), 64 rows/block, grid 512.
// Wave w owns r/z/g cols [32w,32w+32). Flat 16-ks loop, barrier every 4 ks
// (2 slabs staged per phase); B frags in 4 rotating 1-ks buffers, filled
// 3 ks ahead. Gates: a=sigmoid(r+br)*h -> x-region; h stashed in r-acc.
// Tail: 4 groups of 2 kt. Epilogue: h + z*(tanh(g+bh)-h).
// ---------------------------------------------------------------------------
__global__ __launch_bounds__(512, 2)
void gru_fused(const float* __restrict__ x, const float* __restrict__ h,
               const unsigned short* __restrict__ wrz,
               const unsigned short* __restrict__ wg,
               const float* __restrict__ br, const float* __restrict__ bz,
               const float* __restrict__ bh, float* __restrict__ out) {
    __shared__ unsigned short xcA[64 * 512];   // 64 KB

    const int tid  = threadIdx.x;
    const int lane = tid & 63;
    const int wv   = tid >> 6;          // wave 0..7
    const int m0   = lane & 15;
    const int q    = lane >> 4;
    const int rowBase = blockIdx.x * MT;

    float brv[2], bzv[2], bhv[2];
    #pragma unroll
    for (int j = 0; j < 2; ++j) {
        int col = 32 * wv + j * 16 + m0;
        brv[j] = br[col]; bzv[j] = bz[col]; bhv[j] = bh[col];
    }

    // ---- Slab staging geometry: slab s = 64 rows x 64 k (k in [64s,64s+64)).
    const int srow  = tid >> 3;
    const int scol8 = (tid & 7) << 3;
    const float* xrow = x + (size_t)(rowBase + srow) * 256 + scol8;
    const float* hrow = h + (size_t)(rowBase + srow) * 256 + scol8;

    const unsigned short* wrzP = wrz + (size_t)wv * 32768;
    const unsigned short* wgP  = wg  + (size_t)wv * 16384;

    // ---- Preamble: load slabs 0,1; preload B buffers ks=0,1,2; stash slabs.
    f32x4 Sa[2], Sb[2];
    {
        Sa[0] = ld4(xrow);       Sb[0] = ld4(xrow + 4);        // slab 0
        Sa[1] = ld4(xrow + 64);  Sb[1] = ld4(xrow + 68);       // slab 1
    }

    // B buffers: [4 rotating][6 frags]; frag 0..3 = wrz jn, 4..5 = wg j.
    s16x8 Bb[4][6];
    #pragma unroll
    for (int pk = 0; pk < 3; ++pk) {
        #pragma unroll
        for (int jn = 0; jn < 4; ++jn)
            Bb[pk][jn] = *reinterpret_cast<const s16x8*>(
                wrzP + pk * 2048 + jn * 512 + lane * 8);
        #pragma unroll
        for (int j = 0; j < 2; ++j)
            Bb[pk][4 + j] = *reinterpret_cast<const s16x8*>(
                wgP + pk * 1024 + j * 512 + lane * 8);
    }

    stash8(&xcA[lds_idx(srow, scol8)],      Sa[0], Sb[0]);   // slab 0
    stash8(&xcA[lds_idx(srow, 64 + scol8)], Sa[1], Sb[1]);   // slab 1
    asm volatile("s_waitcnt lgkmcnt(0)" ::: "memory");
    __builtin_amdgcn_sched_barrier(0);
    __builtin_amdgcn_s_barrier();
    __builtin_amdgcn_sched_barrier(0);

    f32x4 rz[4][4];     // jn 0,1 = r; jn 2,3 = z
    f32x4 gac[2][4];
    #pragma unroll
    for (int jn = 0; jn < 4; ++jn)
        #pragma unroll
        for (int mt = 0; mt < 4; ++mt)
            rz[jn][mt] = (f32x4){0.f, 0.f, 0.f, 0.f};
    #pragma unroll
    for (int j = 0; j < 2; ++j)
        #pragma unroll
        for (int mt = 0; mt < 4; ++mt)
            gac[j][mt] = (f32x4){0.f, 0.f, 0.f, 0.f};

    // ---- Main loop: flat ks 0..15. Barrier phase = 4 ks (2 slabs).
    // ks%4==0 (ks<12): issue loads for slabs ks/2+2, ks/2+3.
    // every ks (ks<13): prefetch B buffer for ks+3 (3-deep rotation).
    // ks%4==3 (ks<15): stash 2 slabs, lgkmcnt(0)+s_barrier (vmcnt NOT
    // drained -- stage/B loads stay in flight across the barrier).
    #pragma unroll
    for (int ks = 0; ks < 16; ++ks) {
        // Slab loads for next phase
        if ((ks & 3) == 0 && ks < 12) {
            #pragma unroll
            for (int k = 0; k < 2; ++k) {
                const int s = ks / 2 + 2 + k;
                const float* p = (s < 4) ? (xrow + 64 * s) : (hrow + 64 * (s - 4));
                Sa[k] = ld4(p); Sb[k] = ld4(p + 4);
            }
        }
        // B prefetch: fill buffer for ks+3
        if (ks < 13) {
            const int kp = ks + 3, buf = kp & 3;
            #pragma unroll
            for (int jn = 0; jn < 4; ++jn)
                Bb[buf][jn] = *reinterpret_cast<const s16x8*>(
                    wrzP + kp * 2048 + jn * 512 + lane * 8);
            if (kp < 8) {
                #pragma unroll
                for (int j = 0; j < 2; ++j)
                    Bb[buf][4 + j] = *reinterpret_cast<const s16x8*>(
                        wgP + kp * 1024 + j * 512 + lane * 8);
            }
        }
        __builtin_amdgcn_sched_barrier(0);   // loads stay above, MFMAs below
        // MFMA ks with buffer ks&3
        {
            const int cur = ks & 3;
            bf16x8 afr[4];
            #pragma unroll
            for (int mt = 0; mt < 4; ++mt) {
                int row = mt * 16 + m0;
                int idx = row * 512 + ((((ks << 2) | q) ^ (row & 7)) << 3);
                afr[mt] = __builtin_bit_cast(bf16x8,
                    *reinterpret_cast<const s16x8*>(&xcA[idx]));
            }
            #pragma unroll
            for (int jn = 0; jn < 4; ++jn) {
                bf16x8 bf = __builtin_bit_cast(bf16x8, Bb[cur][jn]);
                #pragma unroll
                for (int mt = 0; mt < 4; ++mt)
                    rz[jn][mt] = __builtin_amdgcn_mfma_f32_16x16x32_bf16(
                        afr[mt], bf, rz[jn][mt], 0, 0, 0);
            }
            if (ks < 8) {
                #pragma unroll
                for (int j = 0; j < 2; ++j) {
                    bf16x8 bf = __builtin_bit_cast(bf16x8, Bb[cur][4 + j]);
                    #pragma unroll
                    for (int mt = 0; mt < 4; ++mt)
                        gac[j][mt] = __builtin_amdgcn_mfma_f32_16x16x32_bf16(
                            afr[mt], bf, gac[j][mt], 0, 0, 0);
                }
            }
        }
        __builtin_amdgcn_sched_barrier(0);   // keep slab writes below MFMAs
        // Phase end: stash both pending slabs and barrier.
        if ((ks & 3) == 3 && ks < 15) {
            #pragma unroll
            for (int k = 0; k < 2; ++k) {
                const int s = (ks + 1) / 2 + k;
                stash8(&xcA[lds_idx(srow, 64 * s + scol8)], Sa[k], Sb[k]);
            }
            asm volatile("s_waitcnt lgkmcnt(0)" ::: "memory");
            __builtin_amdgcn_sched_barrier(0);
            __builtin_amdgcn_s_barrier();
            __builtin_amdgcn_sched_barrier(0);
        }
    }
    __syncthreads();   // all LDS A-reads done before x-region overwrite

    // ---- Preload tail group 0 (whh pages 8,9) — gates VALU hides latency
    s16x8 Tb[2][4];
    #pragma unroll
    for (int k2 = 0; k2 < 2; ++k2)
        #pragma unroll
        for (int j = 0; j < 2; ++j)
            Tb[0][k2 * 2 + j] = *reinterpret_cast<const s16x8*>(
                wgP + (8 + k2) * 1024 + j * 512 + lane * 8);

    // ---- Gates: a = sigmoid(r+br)*h -> LDS x-region (paired HW cvt);
    // stash h in r-acc.
    #pragma unroll
    for (int j = 0; j < 2; ++j) {
        int col = 32 * wv + j * 16 + m0;
        #pragma unroll
        for (int mt = 0; mt < 4; ++mt) {
            #pragma unroll
            for (int rg = 0; rg < 4; rg += 2) {
                int row0 = mt * 16 + q * 4 + rg;
                int row1 = row0 + 1;
                float h0 = b2f(xcA[lds_idx(row0, 256 + col)]);
                float h1 = b2f(xcA[lds_idx(row1, 256 + col)]);
                float a0 = sigmoid_f(rz[j][mt][rg]     + brv[j]) * h0;
                float a1 = sigmoid_f(rz[j][mt][rg + 1] + brv[j]) * h1;
                ushort2 c = pk2(a0, a1);
                xcA[lds_idx(row0, col)] = c.x;
                xcA[lds_idx(row1, col)] = c.y;
                rz[j][mt][rg]     = h0;
                rz[j][mt][rg + 1] = h1;
            }
        }
    }
    __syncthreads();   // a visible to all waves

    // ---- Tail: g += a @ whh, 4 groups x 2 kt, double-buffered + fenced
    #pragma unroll
    for (int tg = 0; tg < 4; ++tg) {
        const int cur = tg & 1, nxt = cur ^ 1;
        if (tg < 3) {
            #pragma unroll
            for (int k2 = 0; k2 < 2; ++k2)
                #pragma unroll
                for (int j = 0; j < 2; ++j)
                    Tb[nxt][k2 * 2 + j] = *reinterpret_cast<const s16x8*>(
                        wgP + (10 + tg * 2 + k2) * 1024 + j * 512 + lane * 8);
        }
        __builtin_amdgcn_sched_barrier(0);
        #pragma unroll
        for (int k2 = 0; k2 < 2; ++k2) {
            int kt = tg * 2 + k2;
            bf16x8 afr[4];
            #pragma unroll
            for (int mt = 0; mt < 4; ++mt) {
                int row = mt * 16 + m0;
                int idx = row * 512 + ((((kt << 2) | q) ^ (row & 7)) << 3);
                afr[mt] = __builtin_bit_cast(bf16x8,
                    *reinterpret_cast<const s16x8*>(&xcA[idx]));
            }
            #pragma unroll
            for (int j = 0; j < 2; ++j) {
                bf16x8 bf = __builtin_bit_cast(bf16x8, Tb[cur][k2 * 2 + j]);
                #pragma unroll
                for (int mt = 0; mt < 4; ++mt)
                    gac[j][mt] = __builtin_amdgcn_mfma_f32_16x16x32_bf16(
                        afr[mt], bf, gac[j][mt], 0, 0, 0);
            }
        }
    }

    // ---- Epilogue: h_out = h + z*(tanh(g+bh) - h)
    #pragma unroll
    for (int j = 0; j < 2; ++j) {
        int col = 32 * wv + j * 16 + m0;
        #pragma unroll
        for (int mt = 0; mt < 4; ++mt) {
            #pragma unroll
            for (int rg = 0; rg < 4; ++rg) {
                int row = mt * 16 + q * 4 + rg;
                float zs = sigmoid_f(rz[2 + j][mt][rg] + bzv[j]);
                float gv = tanh_f(gac[j][mt][rg] + bhv[j]);
                float hval = rz[j][mt][rg];
                out[(size_t)(rowBase + row) * 256 + col] = hval + zs * (gv - hval);
            }
        }
    }
}

extern "C" void kernel_launch(void* const* d_in, const int* in_sizes, int n_in,
                              void* d_out, int out_size, void* d_ws, size_t ws_size,
                              hipStream_t stream) {
    const float* x   = (const float*)d_in[0];
    const float* h   = (const float*)d_in[1];
    const float* wr  = (const float*)d_in[2];
    const float* wz  = (const float*)d_in[3];
    const float* whh = (const float*)d_in[4];
    const float* whx = (const float*)d_in[5];
    const float* br  = (const float*)d_in[6];
    const float* bz  = (const float*)d_in[7];
    const float* bh  = (const float*)d_in[8];
    float* out = (float*)d_out;

    unsigned short* wrz = (unsigned short*)d_ws;       // 512 KB
    unsigned short* wg  = wrz + WRZ_ELEMS;             // 256 KB

    prep_weights<<<192, 256, 0, stream>>>(wr, wz, whh, whx, wrz, wg);
    gru_fused<<<B_TOT / MT, 512, 0, stream>>>(x, h, wrz, wg, br, bz, bh, out);
}